// Round 16
// baseline (379.886 us; speedup 1.0000x reference)
//
#include <hip/hip_runtime.h>
#include <hip/hip_fp16.h>

#define NN 50000
#define NE 800000
#define NG 64
#define NC 10
#define BN_EPS 1e-5f
#define NSB 196   // ceil(NN/256)

typedef __attribute__((ext_vector_type(2))) _Float16 h2v;
typedef __attribute__((ext_vector_type(8))) _Float16 f16x8;
typedef __attribute__((ext_vector_type(4))) float f32x4;

__device__ __forceinline__ float2 up2(unsigned u) {
    __half2 h = *reinterpret_cast<__half2*>(&u);
    return __half22float2(h);
}
__device__ __forceinline__ unsigned pk2(float a, float b) {
    __half2 h = __floats2half2_rn(a, b);
    return *reinterpret_cast<unsigned*>(&h);
}

// ---------------- CSR build ----------------

__global__ void deg_count_kernel(const int* __restrict__ dst, int* __restrict__ deg,
                                 unsigned short* __restrict__ pos16) {
    int e = blockIdx.x * blockDim.x + threadIdx.x;
    if (e < NE) {
        int d = __builtin_nontemporal_load(&dst[e]);
        unsigned short p = (unsigned short)atomicAdd(&deg[d], 1);
        __builtin_nontemporal_store(p, &pos16[e]);
    }
}

__global__ __launch_bounds__(256) void block_sum_kernel(const int* __restrict__ deg,
                                                        int* __restrict__ bsum) {
    int b = blockIdx.x, t = threadIdx.x;
    int n = b * 256 + t;
    int v = (n < NN) ? deg[n] : 0;
    __shared__ int red[256];
    red[t] = v;
    __syncthreads();
    for (int off = 128; off > 0; off >>= 1) {
        if (t < off) red[t] += red[t + off];
        __syncthreads();
    }
    if (t == 0) bsum[b] = red[0];
}

__global__ __launch_bounds__(256) void bsum_scan_kernel(const int* __restrict__ bsum,
                                                        int* __restrict__ boff) {
    __shared__ int s[256];
    int t = threadIdx.x;
    int v = (t < NSB) ? bsum[t] : 0;
    s[t] = v;
    __syncthreads();
    for (int off = 1; off < 256; off <<= 1) {
        int cur = s[t];
        int add = (t >= off) ? s[t - off] : 0;
        __syncthreads();
        s[t] = cur + add;
        __syncthreads();
    }
    if (t < NSB) boff[t] = s[t] - v;
}

__global__ __launch_bounds__(256) void csr_setup_kernel(const int* __restrict__ deg,
                                                        const int* __restrict__ boff,
                                                        int* __restrict__ row_off,
                                                        float* __restrict__ dinv,
                                                        float* __restrict__ rdeg) {
    int b = blockIdx.x, t = threadIdx.x;
    int n = b * 256 + t;
    int v = (n < NN) ? deg[n] : 0;
    __shared__ int s[256];
    s[t] = v;
    __syncthreads();
    for (int off = 1; off < 256; off <<= 1) {
        int cur = s[t];
        int add = (t >= off) ? s[t - off] : 0;
        __syncthreads();
        s[t] = cur + add;
        __syncthreads();
    }
    int excl = s[t] - v + boff[b];
    if (n < NN) {
        row_off[n] = excl;
        float d = (float)v + 1.0f;
        dinv[n] = rsqrtf(d);
        rdeg[n] = sqrtf(d);
    }
    if (n == NN - 1) row_off[NN] = NE;
}

__global__ void scatter_pass_kernel(const int* __restrict__ src, const int* __restrict__ dst,
                                    const unsigned short* __restrict__ pos16,
                                    const int* __restrict__ row_off,
                                    int* __restrict__ csr_src, int d0, int d1) {
    int e = blockIdx.x * blockDim.x + threadIdx.x;
    if (e >= NE) return;
    int d = __builtin_nontemporal_load(&dst[e]);
    if (d < d0 || d >= d1) return;
    int s = __builtin_nontemporal_load(&src[e]);
    int p = (int)__builtin_nontemporal_load(&pos16[e]);
    csr_src[row_off[d] + p] = s;
}

__global__ void arow_kernel(const int* __restrict__ row_off, const int* __restrict__ csr_src,
                            const float* __restrict__ dinv, float* __restrict__ arow) {
    int n = blockIdx.x * 256 + threadIdx.x;
    if (n >= NN) return;
    float dv = dinv[n];
    float s = dv;
    int e0 = row_off[n], e1 = row_off[n + 1];
    for (int i = e0; i < e1; ++i) s += dinv[csr_src[i]];
    arow[n] = dv * s;
}

// ---------------- BN stats (layer 0 only) ----------------

__global__ __launch_bounds__(256) void bn_stats_kernel(const __half* __restrict__ h,
                                                       const float* __restrict__ rdeg,
                                                       const float* __restrict__ alpha_p,
                                                       float* __restrict__ stats) {
    float alpha = alpha_p[0];
    int tid = threadIdx.x;
    int c8 = (tid & 7) * 8;
    int rg = tid >> 3;
    float sm[8], sq[8];
#pragma unroll
    for (int k = 0; k < 8; ++k) { sm[k] = 0.f; sq[k] = 0.f; }
    for (int n = blockIdx.x * 32 + rg; n < NN; n += gridDim.x * 32) {
        float rd = rdeg[n];
        uint4 u = *(const uint4*)&h[(size_t)n * 64 + c8];
        float2 p0 = up2(u.x), p1 = up2(u.y), p2 = up2(u.z), p3 = up2(u.w);
        float e[8] = {p0.x, p0.y, p1.x, p1.y, p2.x, p2.y, p3.x, p3.y};
#pragma unroll
        for (int k = 0; k < 8; ++k) {
            float a = e[k] >= 0.f ? e[k] : alpha * e[k];
            a *= rd;
            sm[k] += a;
            sq[k] += a * a;
        }
    }
    __shared__ float ls[256 * 17];
    float* p = &ls[tid * 17];
#pragma unroll
    for (int k = 0; k < 8; ++k) { p[k] = sm[k]; p[8 + k] = sq[k]; }
    __syncthreads();
    if (tid < 128) {
        int cg = tid >> 4;
        int j = tid & 15;
        float acc = 0.f;
        for (int r = 0; r < 32; ++r) acc += ls[(r * 8 + cg) * 17 + j];
        int ch = cg * 8 + (j & 7);
        atomicAdd(&stats[(j < 8 ? 0 : 64) + ch], acc);
    }
}

// ---------------- CSR gather, full-row, pipelined 8-wide; optional epilogue BN-stats ----------------
// OUT 0: dv*sum + bias   OUT 1: dv*(dv*sum + bias)   OUT 2: dv*sum
// STATS (only with OUT==1): accumulate sum/sumsq of prelu(dv*sum+bias, alpha_s) into stats[128].

template <bool PRELU, int OUT, bool STATS>
__global__ __launch_bounds__(256) void gather_kernel(const int* __restrict__ row_off,
                                                     const int* __restrict__ csr_src,
                                                     const float* __restrict__ dinv,
                                                     const float* __restrict__ bias,
                                                     const float* __restrict__ alpha_p,
                                                     const __half* __restrict__ hh,
                                                     __half* __restrict__ outp,
                                                     const float* __restrict__ alpha_s_p,
                                                     float* __restrict__ stats) {
    static_assert(!STATS || OUT == 1, "STATS requires OUT==1");
    int tid = threadIdx.x;
    int r = blockIdx.x * 32 + (tid >> 3);
    int c = (tid & 7) * 8;
    bool valid = r < NN;
    if constexpr (!STATS) {
        if (!valid) return;
    }
    int rr = valid ? r : 0;
    float alpha = 0.f;
    if constexpr (PRELU) alpha = alpha_p[0];
    float acc[8];
    {
        uint4 u0 = *(const uint4*)&hh[(size_t)rr * 64 + c];
        float2 p0 = up2(u0.x), p1 = up2(u0.y), p2 = up2(u0.z), p3 = up2(u0.w);
        acc[0] = p0.x; acc[1] = p0.y; acc[2] = p1.x; acc[3] = p1.y;
        acc[4] = p2.x; acc[5] = p2.y; acc[6] = p3.x; acc[7] = p3.y;
        if constexpr (PRELU) {
#pragma unroll
            for (int k = 0; k < 8; ++k) acc[k] = acc[k] >= 0.f ? acc[k] : alpha * acc[k];
        }
    }
    int beg = valid ? row_off[rr] : 0;
    int end = valid ? row_off[rr + 1] : 0;
    int nct = (end - beg + 7) >> 3;
    int base = beg;
    int q[8];
    if (nct > 0) {
#pragma unroll
        for (int j = 0; j < 8; ++j) {
            int pos = base + j;
            q[j] = csr_src[pos < end ? pos : end - 1];
        }
    }
    for (int it = 0; it < nct; ++it) {
        int s[8];
#pragma unroll
        for (int j = 0; j < 8; ++j) s[j] = q[j];
        int cbase = base;
        base += 8;
        if (it + 1 < nct) {
#pragma unroll
            for (int j = 0; j < 8; ++j) {
                int pos = base + j;
                q[j] = csr_src[pos < end ? pos : end - 1];
            }
        }
        uint4 v[8];
#pragma unroll
        for (int j = 0; j < 8; ++j) v[j] = *(const uint4*)&hh[(size_t)s[j] * 64 + c];
#pragma unroll
        for (int j = 0; j < 8; ++j) {
            float m = (cbase + j < end) ? 1.f : 0.f;
            float2 p0 = up2(v[j].x), p1 = up2(v[j].y), p2 = up2(v[j].z), p3 = up2(v[j].w);
            float e[8] = {p0.x, p0.y, p1.x, p1.y, p2.x, p2.y, p3.x, p3.y};
            if constexpr (PRELU) {
#pragma unroll
                for (int k = 0; k < 8; ++k) e[k] = e[k] >= 0.f ? e[k] : alpha * e[k];
            }
#pragma unroll
            for (int k = 0; k < 8; ++k) acc[k] = fmaf(e[k], m, acc[k]);
        }
    }
    float dv = dinv[rr];
    float o[8];
    if constexpr (OUT == 2) {
#pragma unroll
        for (int k = 0; k < 8; ++k) o[k] = dv * acc[k];
    } else {
        float4 b0 = *(const float4*)&bias[c];
        float4 b1 = *(const float4*)&bias[c + 4];
        float bl[8] = {b0.x, b0.y, b0.z, b0.w, b1.x, b1.y, b1.z, b1.w};
#pragma unroll
        for (int k = 0; k < 8; ++k) o[k] = dv * acc[k] + bl[k];
        if constexpr (STATS) {
            // o[] currently holds true-scale h for the next layer; accumulate BN stats
            float als = alpha_s_p[0];
            __shared__ float ls[256 * 17];
            float* p = &ls[tid * 17];
#pragma unroll
            for (int k = 0; k < 8; ++k) {
                float u = valid ? o[k] : 0.f;
                float sp = u >= 0.f ? u : als * u;
                p[k] = sp;
                p[8 + k] = sp * sp;
            }
            __syncthreads();
            if (tid < 128) {
                int cg = tid >> 4;
                int j = tid & 15;
                float accs = 0.f;
                for (int rw = 0; rw < 32; ++rw) accs += ls[(rw * 8 + cg) * 17 + j];
                int ch = cg * 8 + (j & 7);
                atomicAdd(&stats[(j < 8 ? 0 : 64) + ch], accs);
            }
        }
        if constexpr (OUT == 1) {
#pragma unroll
            for (int k = 0; k < 8; ++k) o[k] *= dv;
        }
    }
    if (valid) {
        uint4 ov;
        ov.x = pk2(o[0], o[1]);
        ov.y = pk2(o[2], o[3]);
        ov.z = pk2(o[4], o[5]);
        ov.w = pk2(o[6], o[7]);
        *(uint4*)&outp[(size_t)r * 64 + c] = ov;
    }
}

// ---------------- MFMA pre-linear: hA16 = dinv * (x_f32 @ W + bias) ----------------

__global__ __launch_bounds__(256) void mfma_pre_kernel(const float* __restrict__ x,
                                                       const float* __restrict__ W,
                                                       __half* __restrict__ outp,
                                                       const float* __restrict__ bias,
                                                       const float* __restrict__ dinv) {
    __shared__ _Float16 At[128][72];
    __shared__ _Float16 Wt[64][72];
    int tid = threadIdx.x;
    for (int i = tid; i < 64 * 32; i += 256) {
        int j = i & 63;
        int k2 = i >> 6;
        *(unsigned*)&Wt[j][2 * k2] = pk2(W[(2 * k2) * 64 + j], W[(2 * k2 + 1) * 64 + j]);
    }
    int r0 = blockIdx.x * 128;
    for (int i = tid; i < 128 * 16; i += 256) {
        int row = i >> 4;
        int k4 = (i & 15) * 4;
        int rr = r0 + row;
        if (rr > NN - 1) rr = NN - 1;
        float4 v = *(const float4*)&x[(size_t)rr * 64 + k4];
        *(unsigned*)&At[row][k4]     = pk2(v.x, v.y);
        *(unsigned*)&At[row][k4 + 2] = pk2(v.z, v.w);
    }
    __syncthreads();
    int w = tid >> 6;
    int l = tid & 63;
    int lr = l & 15;
    int lk = (l >> 4) * 8;
    f32x4 acc[2][4];
#pragma unroll
    for (int rt = 0; rt < 2; ++rt)
#pragma unroll
        for (int ct = 0; ct < 4; ++ct) acc[rt][ct] = (f32x4){0.f, 0.f, 0.f, 0.f};
#pragma unroll
    for (int k0 = 0; k0 < 64; k0 += 32) {
        f16x8 a0 = *(const f16x8*)&At[w * 32 + lr][k0 + lk];
        f16x8 a1 = *(const f16x8*)&At[w * 32 + 16 + lr][k0 + lk];
#pragma unroll
        for (int ct = 0; ct < 4; ++ct) {
            f16x8 b = *(const f16x8*)&Wt[ct * 16 + lr][k0 + lk];
            acc[0][ct] = __builtin_amdgcn_mfma_f32_16x16x32_f16(a0, b, acc[0][ct], 0, 0, 0);
            acc[1][ct] = __builtin_amdgcn_mfma_f32_16x16x32_f16(a1, b, acc[1][ct], 0, 0, 0);
        }
    }
    int rowbase = r0 + w * 32 + (l >> 4) * 4;
#pragma unroll
    for (int rt = 0; rt < 2; ++rt) {
#pragma unroll
        for (int ct = 0; ct < 4; ++ct) {
            int col = ct * 16 + lr;
            float bb = bias[col];
#pragma unroll
            for (int r = 0; r < 4; ++r) {
                int row = rowbase + rt * 16 + r;
                if (row < NN)
                    outp[(size_t)row * 64 + col] = __float2half((acc[rt][ct][r] + bb) * dinv[row]);
            }
        }
    }
}

// ---------------- fused MFMA block MLP (in place on t16) ----------------

__global__ __launch_bounds__(256) void mfma_mlp_kernel(__half* __restrict__ t,
                                                       const float* __restrict__ W1,
                                                       const float* __restrict__ b1,
                                                       const float* __restrict__ W2,
                                                       const float* __restrict__ alpha2_p,
                                                       const float* __restrict__ stats,
                                                       const float* __restrict__ gamma,
                                                       const float* __restrict__ beta,
                                                       const float* __restrict__ arow,
                                                       const float* __restrict__ dinv) {
    __shared__ __align__(16) char smem[45056];
    auto Wt1 = (_Float16(*)[72])smem;
    auto Wt2 = (_Float16(*)[136])smem;
    auto At  = (_Float16(*)[72])(smem + 18432);
    auto Ut  = (_Float16(*)[136])(smem + 27648);
    __shared__ float scS[64], shS[64];
    int tid = threadIdx.x;
    if (tid < 64) {
        float mean = stats[tid] * (1.0f / NN);
        float var  = stats[64 + tid] * (1.0f / NN) - mean * mean;
        float sc = gamma[tid] * rsqrtf(var + BN_EPS);
        scS[tid] = sc;
        shS[tid] = beta[tid] - mean * sc;
    }
    for (int i = tid; i < 128 * 32; i += 256) {
        int j = i & 127;
        int k2 = i >> 7;
        *(unsigned*)&Wt1[j][2 * k2] = pk2(W1[(2 * k2) * 128 + j], W1[(2 * k2 + 1) * 128 + j]);
    }
    int r0 = blockIdx.x * 64;
    for (int i = tid; i < 64 * 16; i += 256) {
        int row = i >> 4;
        int k4 = (i & 15) * 4;
        int rr = r0 + row;
        if (rr > NN - 1) rr = NN - 1;
        uint2 uu = *(const uint2*)&t[(size_t)rr * 64 + k4];
        float2 lo = up2(uu.x), hi = up2(uu.y);
        float av = arow[rr];
        float vx = lo.x * scS[k4 + 0] + shS[k4 + 0] * av;
        float vy = lo.y * scS[k4 + 1] + shS[k4 + 1] * av;
        float vz = hi.x * scS[k4 + 2] + shS[k4 + 2] * av;
        float vw = hi.y * scS[k4 + 3] + shS[k4 + 3] * av;
        *(unsigned*)&At[row][k4]     = pk2(vx, vy);
        *(unsigned*)&At[row][k4 + 2] = pk2(vz, vw);
    }
    __syncthreads();
    int w = tid >> 6;
    int l = tid & 63;
    int lr = l & 15;
    int lk = (l >> 4) * 8;
    int rloc = w * 16 + (l >> 4) * 4;
    {
        f32x4 acc[8];
#pragma unroll
        for (int ct = 0; ct < 8; ++ct) acc[ct] = (f32x4){0.f, 0.f, 0.f, 0.f};
#pragma unroll
        for (int k0 = 0; k0 < 64; k0 += 32) {
            f16x8 a = *(const f16x8*)&At[w * 16 + lr][k0 + lk];
#pragma unroll
            for (int ct = 0; ct < 8; ++ct) {
                f16x8 b = *(const f16x8*)&Wt1[ct * 16 + lr][k0 + lk];
                acc[ct] = __builtin_amdgcn_mfma_f32_16x16x32_f16(a, b, acc[ct], 0, 0, 0);
            }
        }
        float alpha = alpha2_p[0];
#pragma unroll
        for (int ct = 0; ct < 8; ++ct) {
            int col = ct * 16 + lr;
            float bb = b1[col];
#pragma unroll
            for (int r = 0; r < 4; ++r) {
                float v = acc[ct][r] + bb;
                v = v >= 0.f ? v : alpha * v;
                Ut[rloc + r][col] = (_Float16)v;
            }
        }
    }
    __syncthreads();
    for (int i = tid; i < 64 * 64; i += 256) {
        int j = i & 63;
        int k2 = i >> 6;
        *(unsigned*)&Wt2[j][2 * k2] = pk2(W2[(2 * k2) * 64 + j], W2[(2 * k2 + 1) * 64 + j]);
    }
    __syncthreads();
    {
        f32x4 acc[4];
#pragma unroll
        for (int ct = 0; ct < 4; ++ct) acc[ct] = (f32x4){0.f, 0.f, 0.f, 0.f};
#pragma unroll
        for (int k0 = 0; k0 < 128; k0 += 32) {
            f16x8 a = *(const f16x8*)&Ut[w * 16 + lr][k0 + lk];
#pragma unroll
            for (int ct = 0; ct < 4; ++ct) {
                f16x8 b = *(const f16x8*)&Wt2[ct * 16 + lr][k0 + lk];
                acc[ct] = __builtin_amdgcn_mfma_f32_16x16x32_f16(a, b, acc[ct], 0, 0, 0);
            }
        }
#pragma unroll
        for (int ct = 0; ct < 4; ++ct) {
            int col = ct * 16 + lr;
#pragma unroll
            for (int r = 0; r < 4; ++r) {
                int row = r0 + rloc + r;
                if (row < NN) t[(size_t)row * 64 + col] = __float2half(acc[ct][r] * dinv[row]);
            }
        }
    }
}

// ---------------- pool ----------------

__global__ __launch_bounds__(256) void pool_seg_kernel(const __half* __restrict__ h,
                                                       const int* __restrict__ batch,
                                                       float* __restrict__ pooled) {
    int g = blockIdx.x;
    __shared__ int sbeg, send;
    int tid = threadIdx.x;
    if (tid == 0) {
        int lo = 0, hi = NN;
        while (lo < hi) { int mid = (lo + hi) >> 1; if (batch[mid] < g) lo = mid + 1; else hi = mid; }
        sbeg = lo;
        lo = 0; hi = NN;
        while (lo < hi) { int mid = (lo + hi) >> 1; if (batch[mid] < g + 1) lo = mid + 1; else hi = mid; }
        send = lo;
    }
    __syncthreads();
    int beg = sbeg, end = send;
    int c4 = (tid & 15) * 4;
    int rg = tid >> 4;
    float sx = 0, sy = 0, sz = 0, sw = 0;
    for (int n = beg + rg; n < end; n += 16) {
        uint2 u = *(const uint2*)&h[(size_t)n * 64 + c4];
        float2 lo = up2(u.x), hi = up2(u.y);
        sx += lo.x; sy += lo.y; sz += hi.x; sw += hi.y;
    }
    __shared__ float red[256 * 4];
    float* p = &red[tid * 4];
    p[0] = sx; p[1] = sy; p[2] = sz; p[3] = sw;
    __syncthreads();
    if (tid < 64) {
        int cg = tid >> 2;
        int j = tid & 3;
        float acc = 0.f;
        for (int r = 0; r < 16; ++r) acc += red[(r * 16 + cg) * 4 + j];
        float cnt = fmaxf((float)(end - beg), 1.0f);
        pooled[g * 64 + cg * 4 + j] = acc / cnt;
    }
}

// ---------------- head: per-block BN-stats recompute (L2-hot) + fc1 + prelu + fc2 ----------------

__global__ __launch_bounds__(256) void head_fc_kernel(const float* __restrict__ pooled,
                                                      const float* __restrict__ gamma,
                                                      const float* __restrict__ beta,
                                                      const float* __restrict__ fc1w,
                                                      const float* __restrict__ fc1b,
                                                      const float* __restrict__ prelu_p,
                                                      const float* __restrict__ fc2w,
                                                      const float* __restrict__ fc2b,
                                                      float* __restrict__ out) {
    int g = blockIdx.x;
    int tid = threadIdx.x;
    __shared__ float pr[64];
    __shared__ float red[256];
    if (tid < 64) {
        float s = 0.f, q = 0.f;
        for (int gg = 0; gg < 64; ++gg) {
            float v = pooled[gg * 64 + tid];
            s += v; q += v * v;
        }
        float mean = s * (1.0f / 64.0f);
        float var = q * (1.0f / 64.0f) - mean * mean;
        float sc = gamma[tid] * rsqrtf(var + BN_EPS);
        pr[tid] = pooled[g * 64 + tid] * sc + (beta[tid] - mean * sc);
    }
    __syncthreads();
    float alpha = prelu_p[0];
    float o1 = fc1b[tid];
    for (int k = 0; k < 64; ++k) o1 += pr[k] * fc1w[k * 256 + tid];
    o1 = o1 >= 0.f ? o1 : alpha * o1;
    for (int c = 0; c < NC; ++c) {
        red[tid] = o1 * fc2w[tid * NC + c];
        __syncthreads();
        for (int off = 128; off > 0; off >>= 1) {
            if (tid < off) red[tid] += red[tid + off];
            __syncthreads();
        }
        if (tid == 0) out[g * NC + c] = red[0] + fc2b[c];
        __syncthreads();
    }
}

// ---------------- launch ----------------

extern "C" void kernel_launch(void* const* d_in, const int* in_sizes, int n_in,
                              void* d_out, int out_size, void* d_ws, size_t ws_size,
                              hipStream_t stream) {
    const float* x       = (const float*)d_in[0];
    const int*   ei      = (const int*)d_in[1];
    const int*   batch   = (const int*)d_in[2];
    const float* pre_w   = (const float*)d_in[3];
    const float* pre_b   = (const float*)d_in[4];
    const float* bp1     = (const float*)d_in[5];
    const float* bng     = (const float*)d_in[6];
    const float* bnb     = (const float*)d_in[7];
    const float* bw1     = (const float*)d_in[8];
    const float* bb1     = (const float*)d_in[9];
    const float* bp2     = (const float*)d_in[10];
    const float* bw2     = (const float*)d_in[11];
    const float* bb2     = (const float*)d_in[12];
    const float* pgamma  = (const float*)d_in[13];
    const float* pbeta   = (const float*)d_in[14];
    const float* fc1w    = (const float*)d_in[15];
    const float* fc1b    = (const float*)d_in[16];
    const float* pprelu  = (const float*)d_in[17];
    const float* fc2w    = (const float*)d_in[18];
    const float* fc2b    = (const float*)d_in[19];

    const int* src = ei;
    const int* dst = ei + NE;

    __half* hA16 = (__half*)d_ws;                      // [NN,64] prescaled (hs)
    __half* t16  = hA16 + (size_t)NN * 64;             // [NN,64]
    float* dinv  = (float*)(t16 + (size_t)NN * 64);    // [NN]
    float* rdeg  = dinv + NN;                          // [NN]
    float* arow  = rdeg + NN;                          // [NN]
    float* stats = arow + NN;                          // [3*128] (zeroed)
    int*   deg   = (int*)(stats + 3 * 128);            // [NN]    (zeroed, adjacent)
    float* pooledg = (float*)(deg + NN);               // [64*64]
    int*   csr_src = (int*)(pooledg + 64 * 64);        // [NE]
    int*   row_off = csr_src + NE;                     // [NN+1]
    int*   bsum    = row_off + NN + 1;                 // [NSB]
    int*   boff    = bsum + NSB;                       // [NSB]
    unsigned short* pos16 = (unsigned short*)(boff + NSB);   // [NE]

    hipMemsetAsync(stats, 0, ((size_t)3 * 128 + NN) * 4, stream);

    deg_count_kernel<<<(NE + 255) / 256, 256, 0, stream>>>(dst, deg, pos16);
    block_sum_kernel<<<NSB, 256, 0, stream>>>(deg, bsum);
    bsum_scan_kernel<<<1, 256, 0, stream>>>(bsum, boff);
    csr_setup_kernel<<<NSB, 256, 0, stream>>>(deg, boff, row_off, dinv, rdeg);
    for (int p = 0; p < 2; ++p) {
        int d0 = p * 25000;
        int d1 = (p == 1) ? NN : d0 + 25000;
        scatter_pass_kernel<<<(NE + 255) / 256, 256, 0, stream>>>(
            src, dst, pos16, row_off, csr_src, d0, d1);
    }
    arow_kernel<<<(NN + 255) / 256, 256, 0, stream>>>(row_off, csr_src, dinv, arow);

    // pre-linear: hA16 = dinv * (x @ pre_w + pre_b)   (MFMA)
    mfma_pre_kernel<<<(NN + 127) / 128, 256, 0, stream>>>(x, pre_w, hA16, pre_b, dinv);

    // layer-0 BN stats (layers 1,2 stats come fused from the producing gather)
    bn_stats_kernel<<<512, 256, 0, stream>>>(hA16, rdeg, bp1, stats);

    int ggrid = (NN + 31) / 32;
    for (int i = 0; i < 3; ++i) {
        const float* a1 = bp1 + i;
        const float* a2 = bp2 + i;
        const float* gm = bng + i * 64;
        const float* bt = bnb + i * 64;
        const float* w1 = bw1 + (size_t)i * 64 * 128;
        const float* b1 = bb1 + i * 128;
        const float* w2 = bw2 + (size_t)i * 128 * 64;
        const float* b2 = bb2 + i * 64;
        float* st = stats + i * 128;

        // t16 = A_hat @ prelu(h)  (true scale)
        gather_kernel<true, 2, false><<<ggrid, 256, 0, stream>>>(
            row_off, csr_src, dinv, nullptr, a1, hA16, t16, nullptr, nullptr);
        // t16 <- dinv * ( prelu( BN'(t16) @ w1 + b1 ) @ w2 )  (fused MFMA MLP)
        mfma_mlp_kernel<<<(NN + 63) / 64, 256, 0, stream>>>(
            t16, w1, b1, w2, a2, st, gm, bt, arow, dinv);
        // hA16 = A_hat @ t16 + b2; for i<2 also accumulate next layer's BN stats
        if (i < 2) {
            gather_kernel<false, 1, true><<<ggrid, 256, 0, stream>>>(
                row_off, csr_src, dinv, b2, nullptr, t16, hA16,
                bp1 + (i + 1), stats + (i + 1) * 128);
        } else {
            gather_kernel<false, 0, false><<<ggrid, 256, 0, stream>>>(
                row_off, csr_src, dinv, b2, nullptr, t16, hA16, nullptr, nullptr);
        }
    }

    pool_seg_kernel<<<NG, 256, 0, stream>>>(hA16, batch, pooledg);
    head_fc_kernel<<<NG, 256, 0, stream>>>(pooledg, pgamma, pbeta, fc1w, fc1b, pprelu,
                                           fc2w, fc2b, (float*)d_out);
}

// Round 17
// 336.388 us; speedup vs baseline: 1.1293x; 1.1293x over previous
//
#include <hip/hip_runtime.h>
#include <hip/hip_fp16.h>

#define NN 50000
#define NE 800000
#define NG 64
#define NC 10
#define BN_EPS 1e-5f
#define NSB 196   // ceil(NN/256)

typedef __attribute__((ext_vector_type(2))) _Float16 h2v;
typedef __attribute__((ext_vector_type(8))) _Float16 f16x8;
typedef __attribute__((ext_vector_type(4))) float f32x4;

__device__ __forceinline__ float2 up2(unsigned u) {
    __half2 h = *reinterpret_cast<__half2*>(&u);
    return __half22float2(h);
}
__device__ __forceinline__ unsigned pk2(float a, float b) {
    __half2 h = __floats2half2_rn(a, b);
    return *reinterpret_cast<unsigned*>(&h);
}
__device__ __forceinline__ float fdot2u(unsigned a, unsigned b, float c) {
    return __builtin_amdgcn_fdot2(__builtin_bit_cast(h2v, a), __builtin_bit_cast(h2v, b), c, false);
}

// ---------------- CSR build ----------------

__global__ void deg_count_kernel(const int* __restrict__ dst, int* __restrict__ deg,
                                 unsigned short* __restrict__ pos16) {
    int e = blockIdx.x * blockDim.x + threadIdx.x;
    if (e < NE) {
        int d = __builtin_nontemporal_load(&dst[e]);
        unsigned short p = (unsigned short)atomicAdd(&deg[d], 1);
        __builtin_nontemporal_store(p, &pos16[e]);
    }
}

__global__ __launch_bounds__(256) void block_sum_kernel(const int* __restrict__ deg,
                                                        int* __restrict__ bsum) {
    int b = blockIdx.x, t = threadIdx.x;
    int n = b * 256 + t;
    int v = (n < NN) ? deg[n] : 0;
    __shared__ int red[256];
    red[t] = v;
    __syncthreads();
    for (int off = 128; off > 0; off >>= 1) {
        if (t < off) red[t] += red[t + off];
        __syncthreads();
    }
    if (t == 0) bsum[b] = red[0];
}

__global__ __launch_bounds__(256) void bsum_scan_kernel(const int* __restrict__ bsum,
                                                        int* __restrict__ boff) {
    __shared__ int s[256];
    int t = threadIdx.x;
    int v = (t < NSB) ? bsum[t] : 0;
    s[t] = v;
    __syncthreads();
    for (int off = 1; off < 256; off <<= 1) {
        int cur = s[t];
        int add = (t >= off) ? s[t - off] : 0;
        __syncthreads();
        s[t] = cur + add;
        __syncthreads();
    }
    if (t < NSB) boff[t] = s[t] - v;
}

__global__ __launch_bounds__(256) void csr_setup_kernel(const int* __restrict__ deg,
                                                        const int* __restrict__ boff,
                                                        int* __restrict__ row_off,
                                                        float* __restrict__ dinv,
                                                        float* __restrict__ rdeg) {
    int b = blockIdx.x, t = threadIdx.x;
    int n = b * 256 + t;
    int v = (n < NN) ? deg[n] : 0;
    __shared__ int s[256];
    s[t] = v;
    __syncthreads();
    for (int off = 1; off < 256; off <<= 1) {
        int cur = s[t];
        int add = (t >= off) ? s[t - off] : 0;
        __syncthreads();
        s[t] = cur + add;
        __syncthreads();
    }
    int excl = s[t] - v + boff[b];
    if (n < NN) {
        row_off[n] = excl;
        float d = (float)v + 1.0f;
        dinv[n] = rsqrtf(d);
        rdeg[n] = sqrtf(d);
    }
    if (n == NN - 1) row_off[NN] = NE;
}

// partitioned, atomic-free scatter
__global__ void scatter_pass_kernel(const int* __restrict__ src, const int* __restrict__ dst,
                                    const unsigned short* __restrict__ pos16,
                                    const int* __restrict__ row_off,
                                    int* __restrict__ csr_src, int d0, int d1) {
    int e = blockIdx.x * blockDim.x + threadIdx.x;
    if (e >= NE) return;
    int d = __builtin_nontemporal_load(&dst[e]);
    if (d < d0 || d >= d1) return;
    int s = __builtin_nontemporal_load(&src[e]);
    int p = (int)__builtin_nontemporal_load(&pos16[e]);
    csr_src[row_off[d] + p] = s;
}

// arow[n] = dinv[n] * (dinv[n] + sum_e dinv[src_e])
__global__ void arow_kernel(const int* __restrict__ row_off, const int* __restrict__ csr_src,
                            const float* __restrict__ dinv, float* __restrict__ arow) {
    int n = blockIdx.x * 256 + threadIdx.x;
    if (n >= NN) return;
    float dv = dinv[n];
    float s = dv;
    int e0 = row_off[n], e1 = row_off[n + 1];
    for (int i = e0; i < e1; ++i) s += dinv[csr_src[i]];
    arow[n] = dv * s;
}

// ---------------- BN stats over prelu(h_true) where h_true = rdeg * hs ----------------

__global__ __launch_bounds__(256) void bn_stats_kernel(const __half* __restrict__ h,
                                                       const float* __restrict__ rdeg,
                                                       const float* __restrict__ alpha_p,
                                                       float* __restrict__ stats) {
    float alpha = alpha_p[0];
    int tid = threadIdx.x;
    int c4 = (tid & 15) * 4;
    int rg = tid >> 4;
    float sx = 0, sy = 0, sz = 0, sw = 0;
    float qx = 0, qy = 0, qz = 0, qw = 0;
    for (int n = blockIdx.x * 16 + rg; n < NN; n += gridDim.x * 16) {
        float rd = rdeg[n];
        uint2 u = *(const uint2*)&h[(size_t)n * 64 + c4];
        float2 lo = up2(u.x), hi = up2(u.y);
        float a = lo.x >= 0.f ? lo.x : alpha * lo.x;
        float b = lo.y >= 0.f ? lo.y : alpha * lo.y;
        float c = hi.x >= 0.f ? hi.x : alpha * hi.x;
        float d = hi.y >= 0.f ? hi.y : alpha * hi.y;
        a *= rd; b *= rd; c *= rd; d *= rd;
        sx += a; sy += b; sz += c; sw += d;
        qx += a * a; qy += b * b; qz += c * c; qw += d * d;
    }
    __shared__ float ls[256 * 8];
    float* p = &ls[tid * 8];
    p[0] = sx; p[1] = sy; p[2] = sz; p[3] = sw;
    p[4] = qx; p[5] = qy; p[6] = qz; p[7] = qw;
    __syncthreads();
    if (tid < 128) {
        int cidx = tid >> 3;
        int j = tid & 7;
        float acc = 0.f;
        for (int r = 0; r < 16; ++r) acc += ls[(r * 16 + cidx) * 8 + j];
        int ch = cidx * 4 + (j & 3);
        if (j < 4) atomicAdd(&stats[ch], acc);
        else       atomicAdd(&stats[64 + ch], acc);
    }
}

// ---------------- CSR gather, full-row (8 lanes x 8 ch), software-pipelined 8-wide ----------------
// OUT 0: dv*sum + bias   OUT 1: dv*(dv*sum + bias)   OUT 2: dv*sum

template <bool PRELU, int OUT>
__global__ __launch_bounds__(256) void gather_kernel(const int* __restrict__ row_off,
                                                     const int* __restrict__ csr_src,
                                                     const float* __restrict__ dinv,
                                                     const float* __restrict__ bias,
                                                     const float* __restrict__ alpha_p,
                                                     const __half* __restrict__ hh,
                                                     __half* __restrict__ outp) {
    int tid = threadIdx.x;
    int r = blockIdx.x * 32 + (tid >> 3);
    int c = (tid & 7) * 8;
    if (r >= NN) return;
    float alpha = 0.f;
    if constexpr (PRELU) alpha = alpha_p[0];
    float acc[8];
    {
        uint4 u0 = *(const uint4*)&hh[(size_t)r * 64 + c];
        float2 p0 = up2(u0.x), p1 = up2(u0.y), p2 = up2(u0.z), p3 = up2(u0.w);
        acc[0] = p0.x; acc[1] = p0.y; acc[2] = p1.x; acc[3] = p1.y;
        acc[4] = p2.x; acc[5] = p2.y; acc[6] = p3.x; acc[7] = p3.y;
        if constexpr (PRELU) {
#pragma unroll
            for (int k = 0; k < 8; ++k) acc[k] = acc[k] >= 0.f ? acc[k] : alpha * acc[k];
        }
    }
    int beg = row_off[r];
    int end = row_off[r + 1];
    int nct = (end - beg + 7) >> 3;
    int base = beg;
    int q[8];
    if (nct > 0) {
#pragma unroll
        for (int j = 0; j < 8; ++j) {
            int pos = base + j;
            q[j] = csr_src[pos < end ? pos : end - 1];
        }
    }
    for (int it = 0; it < nct; ++it) {
        int s[8];
#pragma unroll
        for (int j = 0; j < 8; ++j) s[j] = q[j];
        int cbase = base;
        base += 8;
        if (it + 1 < nct) {
#pragma unroll
            for (int j = 0; j < 8; ++j) {
                int pos = base + j;
                q[j] = csr_src[pos < end ? pos : end - 1];
            }
        }
        uint4 v[8];
#pragma unroll
        for (int j = 0; j < 8; ++j) v[j] = *(const uint4*)&hh[(size_t)s[j] * 64 + c];
#pragma unroll
        for (int j = 0; j < 8; ++j) {
            float m = (cbase + j < end) ? 1.f : 0.f;
            float2 p0 = up2(v[j].x), p1 = up2(v[j].y), p2 = up2(v[j].z), p3 = up2(v[j].w);
            float e[8] = {p0.x, p0.y, p1.x, p1.y, p2.x, p2.y, p3.x, p3.y};
            if constexpr (PRELU) {
#pragma unroll
                for (int k = 0; k < 8; ++k) e[k] = e[k] >= 0.f ? e[k] : alpha * e[k];
            }
#pragma unroll
            for (int k = 0; k < 8; ++k) acc[k] = fmaf(e[k], m, acc[k]);
        }
    }
    float dv = dinv[r];
    float o[8];
    if constexpr (OUT == 2) {
#pragma unroll
        for (int k = 0; k < 8; ++k) o[k] = dv * acc[k];
    } else {
        float4 b0 = *(const float4*)&bias[c];
        float4 b1 = *(const float4*)&bias[c + 4];
        float bl[8] = {b0.x, b0.y, b0.z, b0.w, b1.x, b1.y, b1.z, b1.w};
#pragma unroll
        for (int k = 0; k < 8; ++k) o[k] = dv * acc[k] + bl[k];
        if constexpr (OUT == 1) {
#pragma unroll
            for (int k = 0; k < 8; ++k) o[k] *= dv;
        }
    }
    uint4 ov;
    ov.x = pk2(o[0], o[1]);
    ov.y = pk2(o[2], o[3]);
    ov.z = pk2(o[4], o[5]);
    ov.w = pk2(o[6], o[7]);
    *(uint4*)&outp[(size_t)r * 64 + c] = ov;
}

// ---------------- pre-linear GEMM (f32 A): out16 = dinv * (x @ W + bias) ----------------

__global__ __launch_bounds__(256) void gemm_pre_kernel(const float* __restrict__ Af,
                                                       const float* __restrict__ W,
                                                       __half* __restrict__ outp,
                                                       const float* __restrict__ bias,
                                                       const float* __restrict__ dinv) {
    constexpr int K = 64, M = 64, BM = 128;
    constexpr int CG = M / 8;
    constexpr int RG = 256 / CG;
    constexpr int KP = K / 2;
    __shared__ unsigned Wh[KP * M];
    __shared__ unsigned Ahs[BM][KP + 4];
    int tid = threadIdx.x;
    for (int i = tid; i < KP * M; i += 256) {
        int kp = i / M, j = i % M;
        Wh[i] = pk2(W[(2 * kp) * M + j], W[(2 * kp + 1) * M + j]);
    }
    int r0 = blockIdx.x * BM;
    for (int i = tid; i < BM * (K / 4); i += 256) {
        int row = i / (K / 4);
        int k4 = (i % (K / 4)) * 4;
        int rr = r0 + row;
        if (rr > NN - 1) rr = NN - 1;
        float4 v = *(const float4*)&Af[(size_t)rr * K + k4];
        uint2 o;
        o.x = pk2(v.x, v.y);
        o.y = pk2(v.z, v.w);
        *(uint2*)&Ahs[row][k4 >> 1] = o;
    }
    __syncthreads();
    int cg = tid % CG, rg = tid / CG;
    int c = cg * 8;
    float acc[4][8];
#pragma unroll
    for (int r = 0; r < 4; ++r)
#pragma unroll
        for (int j = 0; j < 8; ++j) acc[r][j] = 0.f;
#pragma unroll 4
    for (int kp = 0; kp < KP; kp += 2) {
        uint2 a2[4];
#pragma unroll
        for (int r = 0; r < 4; ++r) a2[r] = *(const uint2*)&Ahs[rg + r * RG][kp];
#pragma unroll
        for (int kk = 0; kk < 2; ++kk) {
            const unsigned* wp = &Wh[(kp + kk) * M + c];
            uint4 w0 = *(const uint4*)wp;
            uint4 w1 = *(const uint4*)(wp + 4);
#pragma unroll
            for (int r = 0; r < 4; ++r) {
                unsigned av = kk ? a2[r].y : a2[r].x;
                acc[r][0] = fdot2u(av, w0.x, acc[r][0]);
                acc[r][1] = fdot2u(av, w0.y, acc[r][1]);
                acc[r][2] = fdot2u(av, w0.z, acc[r][2]);
                acc[r][3] = fdot2u(av, w0.w, acc[r][3]);
                acc[r][4] = fdot2u(av, w1.x, acc[r][4]);
                acc[r][5] = fdot2u(av, w1.y, acc[r][5]);
                acc[r][6] = fdot2u(av, w1.z, acc[r][6]);
                acc[r][7] = fdot2u(av, w1.w, acc[r][7]);
            }
        }
    }
    float4 b0 = *(const float4*)&bias[c];
    float4 b1 = *(const float4*)&bias[c + 4];
#pragma unroll
    for (int r = 0; r < 4; ++r) {
        int row = r0 + rg + r * RG;
        if (row < NN) {
            float sc = dinv[row];
            uint4 o;
            o.x = pk2((acc[r][0] + b0.x) * sc, (acc[r][1] + b0.y) * sc);
            o.y = pk2((acc[r][2] + b0.z) * sc, (acc[r][3] + b0.w) * sc);
            o.z = pk2((acc[r][4] + b1.x) * sc, (acc[r][5] + b1.y) * sc);
            o.w = pk2((acc[r][6] + b1.z) * sc, (acc[r][7] + b1.w) * sc);
            *(uint4*)&outp[(size_t)row * M + c] = o;
        }
    }
}

// ---------------- fused MFMA block MLP (in place on t16) ----------------
// t <- dinv * ( prelu( BN'(t) @ W1 + b1 ) @ W2 ), BM=64, 4 waves, U kept in LDS.
// A-frag: row=l&15, k=(l>>4)*8+j.  D: col=l&15, row=(l>>4)*4+reg.  [learn_hip m89/m97]

__global__ __launch_bounds__(256) void mfma_mlp_kernel(__half* __restrict__ t,
                                                       const float* __restrict__ W1,
                                                       const float* __restrict__ b1,
                                                       const float* __restrict__ W2,
                                                       const float* __restrict__ alpha2_p,
                                                       const float* __restrict__ stats,
                                                       const float* __restrict__ gamma,
                                                       const float* __restrict__ beta,
                                                       const float* __restrict__ arow,
                                                       const float* __restrict__ dinv) {
    __shared__ __align__(16) char smem[45056];
    auto Wt1 = (_Float16(*)[72])smem;             // [128][72]
    auto Wt2 = (_Float16(*)[136])smem;            // [64][136] aliases Wt1
    auto At  = (_Float16(*)[72])(smem + 18432);   // [64][72]
    auto Ut  = (_Float16(*)[136])(smem + 27648);  // [64][136]
    __shared__ float scS[64], shS[64];
    int tid = threadIdx.x;
    if (tid < 64) {
        float mean = stats[tid] * (1.0f / NN);
        float var  = stats[64 + tid] * (1.0f / NN) - mean * mean;
        float sc = gamma[tid] * rsqrtf(var + BN_EPS);
        scS[tid] = sc;
        shS[tid] = beta[tid] - mean * sc;
    }
    for (int i = tid; i < 128 * 32; i += 256) {   // W1^T
        int j = i & 127;
        int k2 = i >> 7;
        *(unsigned*)&Wt1[j][2 * k2] = pk2(W1[(2 * k2) * 128 + j], W1[(2 * k2 + 1) * 128 + j]);
    }
    int r0 = blockIdx.x * 64;
    for (int i = tid; i < 64 * 16; i += 256) {    // A = BN'(t)
        int row = i >> 4;
        int k4 = (i & 15) * 4;
        int rr = r0 + row;
        if (rr > NN - 1) rr = NN - 1;
        uint2 uu = *(const uint2*)&t[(size_t)rr * 64 + k4];
        float2 lo = up2(uu.x), hi = up2(uu.y);
        float av = arow[rr];
        float vx = lo.x * scS[k4 + 0] + shS[k4 + 0] * av;
        float vy = lo.y * scS[k4 + 1] + shS[k4 + 1] * av;
        float vz = hi.x * scS[k4 + 2] + shS[k4 + 2] * av;
        float vw = hi.y * scS[k4 + 3] + shS[k4 + 3] * av;
        *(unsigned*)&At[row][k4]     = pk2(vx, vy);
        *(unsigned*)&At[row][k4 + 2] = pk2(vz, vw);
    }
    __syncthreads();
    int w = tid >> 6;
    int l = tid & 63;
    int lr = l & 15;
    int lk = (l >> 4) * 8;
    int rloc = w * 16 + (l >> 4) * 4;
    {
        f32x4 acc[8];
#pragma unroll
        for (int ct = 0; ct < 8; ++ct) acc[ct] = (f32x4){0.f, 0.f, 0.f, 0.f};
#pragma unroll
        for (int k0 = 0; k0 < 64; k0 += 32) {
            f16x8 a = *(const f16x8*)&At[w * 16 + lr][k0 + lk];
#pragma unroll
            for (int ct = 0; ct < 8; ++ct) {
                f16x8 b = *(const f16x8*)&Wt1[ct * 16 + lr][k0 + lk];
                acc[ct] = __builtin_amdgcn_mfma_f32_16x16x32_f16(a, b, acc[ct], 0, 0, 0);
            }
        }
        float alpha = alpha2_p[0];
#pragma unroll
        for (int ct = 0; ct < 8; ++ct) {
            int col = ct * 16 + lr;
            float bb = b1[col];
#pragma unroll
            for (int r = 0; r < 4; ++r) {
                float v = acc[ct][r] + bb;
                v = v >= 0.f ? v : alpha * v;
                Ut[rloc + r][col] = (_Float16)v;
            }
        }
    }
    __syncthreads();
    for (int i = tid; i < 64 * 64; i += 256) {    // W2^T into the Wt1 region
        int j = i & 63;
        int k2 = i >> 6;
        *(unsigned*)&Wt2[j][2 * k2] = pk2(W2[(2 * k2) * 64 + j], W2[(2 * k2 + 1) * 64 + j]);
    }
    __syncthreads();
    {
        f32x4 acc[4];
#pragma unroll
        for (int ct = 0; ct < 4; ++ct) acc[ct] = (f32x4){0.f, 0.f, 0.f, 0.f};
#pragma unroll
        for (int k0 = 0; k0 < 128; k0 += 32) {
            f16x8 a = *(const f16x8*)&Ut[w * 16 + lr][k0 + lk];
#pragma unroll
            for (int ct = 0; ct < 4; ++ct) {
                f16x8 b = *(const f16x8*)&Wt2[ct * 16 + lr][k0 + lk];
                acc[ct] = __builtin_amdgcn_mfma_f32_16x16x32_f16(a, b, acc[ct], 0, 0, 0);
            }
        }
#pragma unroll
        for (int ct = 0; ct < 4; ++ct) {
            int col = ct * 16 + lr;
#pragma unroll
            for (int r = 0; r < 4; ++r) {
                int row = r0 + rloc + r;
                if (row < NN) t[(size_t)row * 64 + col] = __float2half(acc[ct][r] * dinv[row]);
            }
        }
    }
}

// ---------------- pool ----------------

__global__ __launch_bounds__(256) void pool_seg_kernel(const __half* __restrict__ h,
                                                       const int* __restrict__ batch,
                                                       float* __restrict__ pooled) {
    int g = blockIdx.x;
    __shared__ int sbeg, send;
    int tid = threadIdx.x;
    if (tid == 0) {
        int lo = 0, hi = NN;
        while (lo < hi) { int mid = (lo + hi) >> 1; if (batch[mid] < g) lo = mid + 1; else hi = mid; }
        sbeg = lo;
        lo = 0; hi = NN;
        while (lo < hi) { int mid = (lo + hi) >> 1; if (batch[mid] < g + 1) lo = mid + 1; else hi = mid; }
        send = lo;
    }
    __syncthreads();
    int beg = sbeg, end = send;
    int c4 = (tid & 15) * 4;
    int rg = tid >> 4;
    float sx = 0, sy = 0, sz = 0, sw = 0;
    for (int n = beg + rg; n < end; n += 16) {
        uint2 u = *(const uint2*)&h[(size_t)n * 64 + c4];
        float2 lo = up2(u.x), hi = up2(u.y);
        sx += lo.x; sy += lo.y; sz += hi.x; sw += hi.y;
    }
    __shared__ float red[256 * 4];
    float* p = &red[tid * 4];
    p[0] = sx; p[1] = sy; p[2] = sz; p[3] = sw;
    __syncthreads();
    if (tid < 64) {
        int cg = tid >> 2;
        int j = tid & 3;
        float acc = 0.f;
        for (int r = 0; r < 16; ++r) acc += red[(r * 16 + cg) * 4 + j];
        float cnt = fmaxf((float)(end - beg), 1.0f);
        pooled[g * 64 + cg * 4 + j] = acc / cnt;
    }
}

// ---------------- head ----------------

__global__ __launch_bounds__(64) void head_stats_kernel(const float* __restrict__ pooled,
                                                        const float* __restrict__ gamma,
                                                        const float* __restrict__ beta,
                                                        float* __restrict__ headsc) {
    int ch = threadIdx.x;
    float s = 0.f, q = 0.f;
    for (int g = 0; g < 64; ++g) {
        float v = pooled[g * 64 + ch];
        s += v; q += v * v;
    }
    float mean = s * (1.0f / 64.0f);
    float var = q * (1.0f / 64.0f) - mean * mean;
    float sc = gamma[ch] * rsqrtf(var + BN_EPS);
    headsc[ch] = sc;
    headsc[64 + ch] = beta[ch] - mean * sc;
}

__global__ __launch_bounds__(256) void head_fc_kernel(const float* __restrict__ pooled,
                                                      const float* __restrict__ headsc,
                                                      const float* __restrict__ fc1w,
                                                      const float* __restrict__ fc1b,
                                                      const float* __restrict__ prelu_p,
                                                      const float* __restrict__ fc2w,
                                                      const float* __restrict__ fc2b,
                                                      float* __restrict__ out) {
    int g = blockIdx.x;
    int tid = threadIdx.x;
    __shared__ float pr[64];
    __shared__ float red[256];
    if (tid < 64) pr[tid] = pooled[g * 64 + tid] * headsc[tid] + headsc[64 + tid];
    __syncthreads();
    float alpha = prelu_p[0];
    float o1 = fc1b[tid];
    for (int k = 0; k < 64; ++k) o1 += pr[k] * fc1w[k * 256 + tid];
    o1 = o1 >= 0.f ? o1 : alpha * o1;
    for (int c = 0; c < NC; ++c) {
        red[tid] = o1 * fc2w[tid * NC + c];
        __syncthreads();
        for (int off = 128; off > 0; off >>= 1) {
            if (tid < off) red[tid] += red[tid + off];
            __syncthreads();
        }
        if (tid == 0) out[g * NC + c] = red[0] + fc2b[c];
        __syncthreads();
    }
}

// ---------------- launch ----------------

extern "C" void kernel_launch(void* const* d_in, const int* in_sizes, int n_in,
                              void* d_out, int out_size, void* d_ws, size_t ws_size,
                              hipStream_t stream) {
    const float* x       = (const float*)d_in[0];
    const int*   ei      = (const int*)d_in[1];
    const int*   batch   = (const int*)d_in[2];
    const float* pre_w   = (const float*)d_in[3];
    const float* pre_b   = (const float*)d_in[4];
    const float* bp1     = (const float*)d_in[5];
    const float* bng     = (const float*)d_in[6];
    const float* bnb     = (const float*)d_in[7];
    const float* bw1     = (const float*)d_in[8];
    const float* bb1     = (const float*)d_in[9];
    const float* bp2     = (const float*)d_in[10];
    const float* bw2     = (const float*)d_in[11];
    const float* bb2     = (const float*)d_in[12];
    const float* pgamma  = (const float*)d_in[13];
    const float* pbeta   = (const float*)d_in[14];
    const float* fc1w    = (const float*)d_in[15];
    const float* fc1b    = (const float*)d_in[16];
    const float* pprelu  = (const float*)d_in[17];
    const float* fc2w    = (const float*)d_in[18];
    const float* fc2b    = (const float*)d_in[19];

    const int* src = ei;
    const int* dst = ei + NE;

    __half* hA16 = (__half*)d_ws;                      // [NN,64] prescaled (hs)
    __half* t16  = hA16 + (size_t)NN * 64;             // [NN,64]
    float* dinv  = (float*)(t16 + (size_t)NN * 64);    // [NN]
    float* rdeg  = dinv + NN;                          // [NN]
    float* arow  = rdeg + NN;                          // [NN]
    float* stats = arow + NN;                          // [3*128] (zeroed)
    int*   deg   = (int*)(stats + 3 * 128);            // [NN]    (zeroed, adjacent)
    float* pooledg = (float*)(deg + NN);               // [64*64]
    float* headsc  = pooledg + 64 * 64;                // [128]
    int*   csr_src = (int*)(headsc + 128);             // [NE]
    int*   row_off = csr_src + NE;                     // [NN+1]
    int*   bsum    = row_off + NN + 1;                 // [NSB]
    int*   boff    = bsum + NSB;                       // [NSB]
    unsigned short* pos16 = (unsigned short*)(boff + NSB);   // [NE]

    hipMemsetAsync(stats, 0, ((size_t)3 * 128 + NN) * 4, stream);

    deg_count_kernel<<<(NE + 255) / 256, 256, 0, stream>>>(dst, deg, pos16);
    block_sum_kernel<<<NSB, 256, 0, stream>>>(deg, bsum);
    bsum_scan_kernel<<<1, 256, 0, stream>>>(bsum, boff);
    csr_setup_kernel<<<NSB, 256, 0, stream>>>(deg, boff, row_off, dinv, rdeg);
    for (int p = 0; p < 2; ++p) {
        int d0 = p * 25000;
        int d1 = (p == 1) ? NN : d0 + 25000;
        scatter_pass_kernel<<<(NE + 255) / 256, 256, 0, stream>>>(
            src, dst, pos16, row_off, csr_src, d0, d1);
    }
    arow_kernel<<<(NN + 255) / 256, 256, 0, stream>>>(row_off, csr_src, dinv, arow);

    // pre-linear: hA16 = dinv * (x @ pre_w + pre_b)
    gemm_pre_kernel<<<(NN + 127) / 128, 256, 0, stream>>>(x, pre_w, hA16, pre_b, dinv);

    int ggrid = (NN + 31) / 32;
    for (int i = 0; i < 3; ++i) {
        const float* a1 = bp1 + i;
        const float* a2 = bp2 + i;
        const float* gm = bng + i * 64;
        const float* bt = bnb + i * 64;
        const float* w1 = bw1 + (size_t)i * 64 * 128;
        const float* b1 = bb1 + i * 128;
        const float* w2 = bw2 + (size_t)i * 128 * 64;
        const float* b2 = bb2 + i * 64;
        float* st = stats + i * 128;

        bn_stats_kernel<<<256, 256, 0, stream>>>(hA16, rdeg, a1, st);
        // t16 = A_hat @ prelu(h)  (true scale)
        gather_kernel<true, 2><<<ggrid, 256, 0, stream>>>(
            row_off, csr_src, dinv, nullptr, a1, hA16, t16);
        // t16 <- dinv * ( prelu( BN'(t16) @ w1 + b1 ) @ w2 )  (fused MFMA MLP, in place)
        mfma_mlp_kernel<<<(NN + 63) / 64, 256, 0, stream>>>(
            t16, w1, b1, w2, a2, st, gm, bt, arow, dinv);
        // hA16 = A_hat @ t16 + b2  (prescaled except last block)
        if (i < 2) {
            gather_kernel<false, 1><<<ggrid, 256, 0, stream>>>(
                row_off, csr_src, dinv, b2, nullptr, t16, hA16);
        } else {
            gather_kernel<false, 0><<<ggrid, 256, 0, stream>>>(
                row_off, csr_src, dinv, b2, nullptr, t16, hA16);
        }
    }

    pool_seg_kernel<<<NG, 256, 0, stream>>>(hA16, batch, pooledg);
    head_stats_kernel<<<1, 64, 0, stream>>>(pooledg, pgamma, pbeta, headsc);
    head_fc_kernel<<<NG, 256, 0, stream>>>(pooledg, headsc, fc1w, fc1b, pprelu,
                                           fc2w, fc2b, (float*)d_out);
}